// Round 10
// baseline (329.459 us; speedup 1.0000x reference)
//
#include <hip/hip_runtime.h>
#include <hip/hip_bf16.h>

#define FEAT    512
#define HEADS   4
#define NEG     0.2f

typedef unsigned int uint;
typedef unsigned short ushort_t;
typedef __attribute__((ext_vector_type(8))) short bf16x8v;   // 8 bf16 = 4 VGPRs
typedef __attribute__((ext_vector_type(4))) float f32x4v;    // mfma acc
typedef __attribute__((ext_vector_type(2))) float f32x2v;    // packed-f32 pair
typedef __attribute__((ext_vector_type(4))) uint uint4v;     // nt-load/store 16B
typedef __attribute__((address_space(3))) uint lds_u32_t;
typedef __attribute__((address_space(1))) const uint g_u32_t;

__device__ inline float bf2f(ushort_t h) { return __uint_as_float(((uint)h) << 16); }
__device__ inline ushort_t f2bf(float f) {
    uint u = __float_as_uint(f);
    u += 0x7fff + ((u >> 16) & 1);           // RNE
    return (ushort_t)(u >> 16);
}
// packed-f32 VOP3P ops (1 inst / 2 lanes).
__device__ inline f32x2v pk_add(f32x2v a, f32x2v b) {
    f32x2v d; asm("v_pk_add_f32 %0, %1, %2" : "=v"(d) : "v"(a), "v"(b)); return d;
}
__device__ inline f32x2v pk_fma(f32x2v a, f32x2v b, f32x2v c) {
    f32x2v d; asm("v_pk_fma_f32 %0, %1, %2, %3" : "=v"(d) : "v"(a), "v"(b), "v"(c)); return d;
}
__device__ inline f32x2v up2v(uint d) {      // 2 packed bf16 -> f32x2v, 2 inst
    f32x2v r; r.x = __uint_as_float(d << 16); r.y = __uint_as_float(d & 0xffff0000u); return r;
}
__device__ inline f32x2v pk_min0(f32x2v a) { // no v_pk_min_f32 -> 2 scalar mins
    f32x2v r; r.x = fminf(a.x, 0.f); r.y = fminf(a.y, 0.f); return r;
}

// ---------------------------------------------------------------------------
// mega-prep (R8/R9): ALL preamble work in ONE dispatch.
// block 0        : CSR build entirely in LDS (N<=24576 -> 96KB deg array).
// block 1        : flag write + small-array canon (att/bias/Wc/bc).
// blocks [2,2+nT4): W transpose+canon, 4 64x64 tiles per 1024-thread block.
// blocks rest    : x fp32->bf16 canon (skipped when x already bf16).
// ---------------------------------------------------------------------------
__global__ __launch_bounds__(1024) void mega_kernel(
    const ushort_t* __restrict__ xprobe, int* flag,
    const int* __restrict__ edst, int* __restrict__ offs, int* __restrict__ cur,
    int N, int E,
    const void* a0, ushort_t* o0, int n0, const void* a1, ushort_t* o1, int n1,
    const void* a2, ushort_t* o2, int n2, const void* a3, ushort_t* o3, int n3,
    const void* __restrict__ Wl, const void* __restrict__ Wr,
    ushort_t* __restrict__ WtL, ushort_t* __restrict__ WtR,
    int Kk, int HCk, int nT4b,
    const void* __restrict__ xin, ushort_t* __restrict__ xc, long long nx) {
    __shared__ int smem[24576];              // 96KB: CSR deg / transpose tiles
    __shared__ int s_isbf;
    __shared__ int wtot[16];
    int tid = threadIdx.x;
    int b = blockIdx.x;

    if (b == 0) {                            // ---- CSR build (one block) ----
        int* sdeg = smem;
        for (int i = tid; i < N; i += 1024) sdeg[i] = 0;
        __syncthreads();
        int nE4 = E >> 2;
        for (int i = tid; i < nE4; i += 1024) {
            int4 q = *(const int4*)&edst[i << 2];
            if ((uint)q.x < (uint)N) atomicAdd(&sdeg[q.x], 1);
            if ((uint)q.y < (uint)N) atomicAdd(&sdeg[q.y], 1);
            if ((uint)q.z < (uint)N) atomicAdd(&sdeg[q.z], 1);
            if ((uint)q.w < (uint)N) atomicAdd(&sdeg[q.w], 1);
        }
        for (int i = (nE4 << 2) + tid; i < E; i += 1024) {
            int d = edst[i];
            if ((uint)d < (uint)N) atomicAdd(&sdeg[d], 1);
        }
        __syncthreads();
        int wv = tid >> 6, ln = tid & 63;
        int seg = (N + 15) >> 4;
        int sg0 = wv * seg, sg1 = min(sg0 + seg, N);
        // pass 1: per-segment totals (deg+1 folds in the self-loop)
        int sum = 0;
        for (int i = sg0 + ln; i < sg1; i += 64) sum += sdeg[i] + 1;
        #pragma unroll
        for (int off = 32; off >= 1; off >>= 1) sum += __shfl_xor(sum, off);
        if (ln == 0) wtot[wv] = sum;
        __syncthreads();
        // exclusive scan of the 16 segment totals (wave 0)
        if (wv == 0) {
            int v = (ln < 16) ? wtot[ln] : 0;
            int incl = v;
            #pragma unroll
            for (int off = 1; off < 16; off <<= 1) {
                int t2 = __shfl_up(incl, off);
                if (ln >= off) incl += t2;
            }
            if (ln < 16) wtot[ln] = incl - v;
            if (ln == 15) offs[N] = incl;    // grand total
        }
        __syncthreads();
        // pass 2: exclusive scan within segment, write offsets+cursor
        int carry = wtot[wv];
        for (int i0 = sg0; i0 < sg1; i0 += 64) {
            int i = i0 + ln;
            int v = (i < sg1) ? sdeg[i] + 1 : 0;
            int incl = v;
            #pragma unroll
            for (int off = 1; off < 64; off <<= 1) {
                int t2 = __shfl_up(incl, off);
                if (ln >= off) incl += t2;
            }
            int excl = carry + incl - v;
            if (i < sg1) { offs[i] = excl; cur[i] = excl; }
            carry += __shfl(incl, 63);
        }
        return;
    }

    // ---- dtype probe (all remaining roles) ----
    if (tid < 64) {
        int hits = 0;
        for (int i = tid; i < 128; i += 64) {
            ushort_t w2 = xprobe[2 * i];
            uint hb = (w2 >> 8) & 0x7f;
            hits += (hb >= 0x38 && hb <= 0x42) ? 1 : 0;
        }
        #pragma unroll
        for (int off = 32; off >= 1; off >>= 1) hits += __shfl_xor(hits, off);
        if (tid == 0) s_isbf = (hits >= 64) ? 1 : 0;
    }
    __syncthreads();
    int isbf = s_isbf;

    if (b == 1) {                            // ---- flag + small canon ----
        if (tid == 0) *flag = isbf;
        int total = n0 + n1 + n2 + n3;
        for (int idx0 = tid; idx0 < total; idx0 += 1024) {
            int idx = idx0;
            const void* srcp; ushort_t* dstp;
            if (idx < n0) { srcp = a0; dstp = o0; }
            else { idx -= n0;
              if (idx < n1) { srcp = a1; dstp = o1; }
              else { idx -= n1;
                if (idx < n2) { srcp = a2; dstp = o2; }
                else { idx -= n2; srcp = a3; dstp = o3; } } }
            dstp[idx] = isbf ? ((const ushort_t*)srcp)[idx]
                             : f2bf(((const float*)srcp)[idx]);
        }
        return;
    }
    if (b < 2 + nT4b) {                      // ---- W transpose, 4 tiles/block ----
        typedef ushort_t t64_t[64][72];
        t64_t* t4 = (t64_t*)smem;            // 36864B alias of smem
        int g = (b - 2) * 4 + (tid >> 8);
        int sub = tid & 255;
        int ntk = Kk >> 6;
        int nTiles = (HCk >> 6) * ntk * 2;
        int r = sub >> 3;                    // 0..31
        int c = (sub & 7) * 8;               // 0,8,..,56
        ushort_t (*t)[72] = t4[tid >> 8];
        int z = g & 1;
        int rest = g >> 1;
        int ky = rest % ntk, nxt2 = rest / ntk;
        int kt0 = ky * 64, nt0 = nxt2 * 64;
        if (g < nTiles) {
            const void* in = z ? Wr : Wl;
            #pragma unroll
            for (int p = 0; p < 2; ++p) {
                int row = r + p * 32;
                size_t basei = (size_t)(kt0 + row) * HCk + nt0 + c;
                if (isbf) {
                    *(uint4*)&t[row][c] = *(const uint4*)((const ushort_t*)in + basei);
                } else {
                    const float* f = (const float*)in + basei;
                    float4 aa = *(const float4*)f, bb = *(const float4*)(f + 4);
                    ushort_t o[8] = {f2bf(aa.x), f2bf(aa.y), f2bf(aa.z), f2bf(aa.w),
                                     f2bf(bb.x), f2bf(bb.y), f2bf(bb.z), f2bf(bb.w)};
                    *(uint4*)&t[row][c] = *(uint4*)o;
                }
            }
        }
        __syncthreads();
        if (g < nTiles) {
            ushort_t* outp = z ? WtR : WtL;
            #pragma unroll
            for (int p = 0; p < 2; ++p) {
                int row = r + p * 32;
                #pragma unroll
                for (int j = 0; j < 8; ++j)
                    outp[(size_t)(nt0 + row) * Kk + kt0 + c + j] = t[c + j][row];
            }
        }
        return;
    }
    if (isbf) return;                        // ---- x canon ----
    long long i0 = ((long long)(b - 2 - nT4b) * 1024 + tid) * 8;
    if (i0 + 8 <= nx) {
        const float* f = (const float*)xin + i0;
        float4 aa = *(const float4*)f, bb = *(const float4*)(f + 4);
        ushort_t o[8] = {f2bf(aa.x), f2bf(aa.y), f2bf(aa.z), f2bf(aa.w),
                         f2bf(bb.x), f2bf(bb.y), f2bf(bb.z), f2bf(bb.w)};
        *(uint4*)&xc[i0] = *(uint4*)o;
    } else {
        for (long long i = i0; i < nx; ++i) xc[i] = f2bf(((const float*)xin)[i]);
    }
}

// ---------------------------------------------------------------------------
// Fallback preamble kernels (used only when N > 24576): prep/histx/scans.
// ---------------------------------------------------------------------------
__global__ __launch_bounds__(256) void prep_kernel(
    const ushort_t* __restrict__ xprobe, int* flag,
    int* __restrict__ deg, int N, int NBZ,
    const void* a0, ushort_t* o0, int n0, const void* a1, ushort_t* o1, int n1,
    const void* a2, ushort_t* o2, int n2, const void* a3, ushort_t* o3, int n3,
    const void* __restrict__ Wl, const void* __restrict__ Wr,
    ushort_t* __restrict__ WtL, ushort_t* __restrict__ WtR, int Kk, int HCk) {
    __shared__ int s_isbf;
    __shared__ ushort_t t[64][72];
    int tid = threadIdx.x;
    if (tid < 64) {
        int hits = 0;
        for (int i = tid; i < 128; i += 64) {
            ushort_t w = xprobe[2 * i];
            uint hb = (w >> 8) & 0x7f;
            hits += (hb >= 0x38 && hb <= 0x42) ? 1 : 0;
        }
        #pragma unroll
        for (int off = 32; off >= 1; off >>= 1) hits += __shfl_xor(hits, off);
        if (tid == 0) s_isbf = (hits >= 64) ? 1 : 0;
    }
    __syncthreads();
    int isbf = s_isbf;
    int b = blockIdx.x;
    if (b == 0 && tid == 0) *flag = isbf;

    if (b < NBZ) {                       // zero deg (int4)
        int i0 = (b * 256 + tid) * 4;
        if (i0 + 4 <= N) *(int4*)&deg[i0] = make_int4(0, 0, 0, 0);
        else for (int j = 0; j < 4; ++j) if (i0 + j < N) deg[i0 + j] = 0;
        return;
    }
    if (b < NBZ + 15) {                  // canon small4
        int idx = (b - NBZ) * 256 + tid;
        const void* srcs[4] = {a0, a1, a2, a3};
        ushort_t* dsts[4] = {o0, o1, o2, o3};
        int ns[4] = {n0, n1, n2, n3};
        #pragma unroll
        for (int k = 0; k < 4; ++k) {
            if (idx < ns[k]) {
                dsts[k][idx] = isbf ? ((const ushort_t*)srcs[k])[idx]
                                    : f2bf(((const float*)srcs[k])[idx]);
                return;
            }
            idx -= ns[k];
        }
        return;
    }
    // W transpose+canon: out[HC][K] = in[K][HC]
    int b2 = b - (NBZ + 15);
    int z = b2 & 1;
    int rest = b2 >> 1;
    int ntk = Kk >> 6;
    int ky = rest % ntk, nxt = rest / ntk;
    const void* in = z ? Wr : Wl;
    ushort_t* outp = z ? WtR : WtL;
    int kt0 = ky * 64, nt0 = nxt * 64;
    int r = tid >> 3;
    int c = (tid & 7) * 8;
    #pragma unroll
    for (int p = 0; p < 2; ++p) {
        int row = r + p * 32;
        size_t base = (size_t)(kt0 + row) * HCk + nt0 + c;
        if (isbf) {
            *(uint4*)&t[row][c] = *(const uint4*)((const ushort_t*)in + base);
        } else {
            const float* f = (const float*)in + base;
            float4 a = *(const float4*)f, bb = *(const float4*)(f + 4);
            ushort_t o[8] = {f2bf(a.x), f2bf(a.y), f2bf(a.z), f2bf(a.w),
                             f2bf(bb.x), f2bf(bb.y), f2bf(bb.z), f2bf(bb.w)};
            *(uint4*)&t[row][c] = *(uint4*)o;
        }
    }
    __syncthreads();
    #pragma unroll
    for (int p = 0; p < 2; ++p) {
        int row = r + p * 32;
        #pragma unroll
        for (int j = 0; j < 8; ++j)
            outp[(size_t)(nt0 + row) * Kk + kt0 + c + j] = t[c + j][row];
    }
}

__global__ __launch_bounds__(256) void histx_kernel(
    const ushort_t* __restrict__ xprobe,
    const int* __restrict__ dstE, int* deg, int E, int NH, int Ngr,
    const void* __restrict__ xin, ushort_t* __restrict__ xc, long long nx) {
    int tid = threadIdx.x;
    int b = blockIdx.x;
    if (b < NH) {
        int i = b * 256 + tid;
        if (i < E) {
            int d = dstE[i];
            if ((uint)d < (uint)Ngr) atomicAdd(&deg[d], 1);
        }
        return;
    }
    __shared__ int s_isbf;
    if (tid < 64) {
        int hits = 0;
        for (int i = tid; i < 128; i += 64) {
            ushort_t w = xprobe[2 * i];
            uint hb = (w >> 8) & 0x7f;
            hits += (hb >= 0x38 && hb <= 0x42) ? 1 : 0;
        }
        #pragma unroll
        for (int off = 32; off >= 1; off >>= 1) hits += __shfl_xor(hits, off);
        if (tid == 0) s_isbf = (hits >= 64) ? 1 : 0;
    }
    __syncthreads();
    if (s_isbf) return;
    long long i0 = ((long long)(b - NH) * 256 + tid) * 8;
    if (i0 + 8 <= nx) {
        const float* f = (const float*)xin + i0;
        float4 a = *(const float4*)f, bb = *(const float4*)(f + 4);
        ushort_t o[8] = {f2bf(a.x), f2bf(a.y), f2bf(a.z), f2bf(a.w),
                         f2bf(bb.x), f2bf(bb.y), f2bf(bb.z), f2bf(bb.w)};
        *(uint4*)&xc[i0] = *(uint4*)o;
    } else {
        for (long long i = i0; i < nx; ++i) xc[i] = f2bf(((const float*)xin)[i]);
    }
}

__global__ __launch_bounds__(256) void scan1(const int* __restrict__ deg, int* __restrict__ part,
                                             int* __restrict__ bsum, int N) {
    __shared__ int tmp[256];
    int b = blockIdx.x, tid = threadIdx.x;
    int i0 = b * 1024 + tid * 4;
    int v[4] = {0, 0, 0, 0};
    if (i0 + 4 <= N) { int4 q = *(const int4*)&deg[i0]; v[0]=q.x+1; v[1]=q.y+1; v[2]=q.z+1; v[3]=q.w+1; }
    else { for (int j = 0; j < 4; ++j) v[j] = (i0 + j < N) ? deg[i0 + j] + 1 : 0; }
    int s0 = v[0], s1 = s0 + v[1], s2 = s1 + v[2], s3 = s2 + v[3];
    tmp[tid] = s3;
    __syncthreads();
    for (int off = 1; off < 256; off <<= 1) {
        int t = (tid >= off) ? tmp[tid - off] : 0;
        __syncthreads();
        tmp[tid] += t;
        __syncthreads();
    }
    int base = tid ? tmp[tid - 1] : 0;
    int e[4] = {base, base + s0, base + s1, base + s2};
    if (i0 + 4 <= N) { *(int4*)&part[i0] = make_int4(e[0], e[1], e[2], e[3]); }
    else { for (int j = 0; j < 4; ++j) if (i0 + j < N) part[i0 + j] = e[j]; }
    if (tid == 255) bsum[b] = tmp[255];
}

__global__ __launch_bounds__(256) void scan3(const int* __restrict__ part, const int* __restrict__ bsum,
                                             int* __restrict__ offsets, int* __restrict__ cursor,
                                             int N, int Nb) {
    __shared__ int s_add, s_tot;
    int b = blockIdx.x, tid = threadIdx.x;
    if (tid < 64) {
        int v = (tid < Nb) ? bsum[tid] : 0;
        int incl = v;
        #pragma unroll
        for (int off = 1; off < 64; off <<= 1) {
            int t = __shfl_up(incl, off);
            if (tid >= off) incl += t;
        }
        if (tid == b) s_add = incl - v;
        if (tid == Nb - 1) s_tot = incl;
    }
    __syncthreads();
    int add = s_add;
    int i0 = b * 1024 + tid * 4;
    #pragma unroll
    for (int j = 0; j < 4; ++j) {
        int i = i0 + j;
        if (i < N) { int o = part[i] + add; offsets[i] = o; cursor[i] = o; }
    }
    if (b == Nb - 1 && tid == 0) offsets[N] = s_tot;   // = E + N
}

__global__ void scatter_kernel(const int* __restrict__ src, const int* __restrict__ dst,
                               int* cursor, int* srcs, int E, int N) {
    int i = blockIdx.x * blockDim.x + threadIdx.x;
    if (i >= E + N) return;
    int s, d;
    if (i < E) { s = src[i]; d = dst[i]; }
    else       { s = i - E; d = i - E; }   // self-loop
    if ((uint)d >= (uint)N) return;
    int pos = atomicAdd(&cursor[d], 1);
    if ((uint)pos < (uint)(E + N)) srcs[pos] = s;
}

// ---------------------------------------------------------------------------
// MFMA bf16 GEMM (+ fused scatter rows). C[M,N] = A[M,K] @ Bt[N,K]^T.
// 128x128 tile, 4 waves of 64x64, BK=64. Proven ~115-117us on this shape.
// R10: C-writes for columns >= ntc0 use NONTEMPORAL stores. Rationale: the
// xr half of xlr is read exactly once (streamed) by gat, while the xl half
// is a 737MB-logical random-gather table that fits (82MB) in the 256MB L3 —
// but gat measured 385MB HBM fetch, i.e. ~half the gathers miss L3 because
// the normally-written xr stream + churn evict xl. nt-storing xr keeps L3
// preferentially filled with xl. gat source unchanged -> FETCH delta is
// attributable to this one change.
// ---------------------------------------------------------------------------
__global__ __launch_bounds__(256) void gemm128(const ushort_t* A_bf, const ushort_t* A_cv,
                                               const int* __restrict__ flag,
                                               const ushort_t* __restrict__ Bt,
                                               ushort_t* __restrict__ C,
                                               int M, int Nn, int K, int ntc0, int gyGemm,
                                               const int* __restrict__ esrc,
                                               const int* __restrict__ edst,
                                               int* cursor, int* srcsOut,
                                               int E, int Ngr, int nScB) {
    if ((int)blockIdx.y >= gyGemm) {       // scatter role
        int id = ((int)blockIdx.y - gyGemm) * (int)gridDim.x + (int)blockIdx.x;
        if (id < nScB) {
            int i = id * 256 + (int)threadIdx.x;
            int EN = E + Ngr;
            if (i < EN) {
                int s, d;
                if (i < E) { s = esrc[i]; d = edst[i]; }
                else       { s = i - E; d = i - E; }   // self-loop
                if ((uint)d < (uint)Ngr) {
                    int pos = atomicAdd(&cursor[d], 1);
                    if ((uint)pos < (uint)EN) srcsOut[pos] = s;
                }
            }
        }
        return;
    }
    constexpr int CSTR = 132;                 // epilogue row stride (bank spread)
    __shared__ ushort_t SH[128 * CSTR];       // 33792 B; staging uses first 32KB
    ushort_t* As = SH;                        // As[2][4096]
    ushort_t* Bs = SH + 8192;                 // Bs[2][4096]
    const ushort_t* A = (*flag) ? A_bf : A_cv;
    int tid = threadIdx.x;
    int wave = tid >> 6, lane = tid & 63;
    int row0 = blockIdx.y * 128, col0 = blockIdx.x * 128;
    int wm = (wave >> 1) * 64, wn = (wave & 1) * 64;

    f32x4v acc[4][4];
    #pragma unroll
    for (int i = 0; i < 4; ++i)
        #pragma unroll
        for (int j = 0; j < 4; ++j) acc[i][j] = (f32x4v){0.f, 0.f, 0.f, 0.f};

    int fm = lane & 15, kq8 = (lane >> 4) * 8;

    // staging (coalesced 64B runs): chunk p -> row=p>>2, kp=p&3
    const ushort_t* srcA[2]; ushort_t* dstA0[2]; ushort_t* dstA1[2];
    const ushort_t* srcB[2]; ushort_t* dstB0[2]; ushort_t* dstB1[2];
    #pragma unroll
    for (int i = 0; i < 2; ++i) {
        int p = (wave * 2 + i) * 64 + lane;
        int row = p >> 2, kp = p & 3;
        int gra = row0 + row; if (gra >= M) gra = M - 1;   // tail clamp (C-write guarded)
        srcA[i] = &A[(size_t)gra * K + kp * 8];
        srcB[i] = &Bt[(size_t)(col0 + row) * K + kp * 8];
        dstA0[i] = &As[p * 8]; dstA1[i] = &As[4096 + p * 8];
        dstB0[i] = &Bs[p * 8]; dstB1[i] = &Bs[4096 + p * 8];
    }

    for (int k0 = 0; k0 < K; k0 += 64) {
        #pragma unroll
        for (int i = 0; i < 2; ++i) {
            __builtin_amdgcn_global_load_lds((g_u32_t*)srcA[i],        (lds_u32_t*)dstA0[i], 16, 0, 0);
            __builtin_amdgcn_global_load_lds((g_u32_t*)(srcA[i] + 32), (lds_u32_t*)dstA1[i], 16, 0, 0);
            __builtin_amdgcn_global_load_lds((g_u32_t*)srcB[i],        (lds_u32_t*)dstB0[i], 16, 0, 0);
            __builtin_amdgcn_global_load_lds((g_u32_t*)(srcB[i] + 32), (lds_u32_t*)dstB1[i], 16, 0, 0);
            srcA[i] += 64; srcB[i] += 64;
        }
        __syncthreads();

        #pragma unroll
        for (int panel = 0; panel < 2; ++panel) {
            bf16x8v af[4], bfr[4];
            #pragma unroll
            for (int mi = 0; mi < 4; ++mi)
                af[mi] = *(const bf16x8v*)&As[panel * 4096 + (wm + mi * 16 + fm) * 32 + kq8];
            #pragma unroll
            for (int nj = 0; nj < 4; ++nj)
                bfr[nj] = *(const bf16x8v*)&Bs[panel * 4096 + (wn + nj * 16 + fm) * 32 + kq8];
            #pragma unroll
            for (int mi = 0; mi < 4; ++mi)
                #pragma unroll
                for (int nj = 0; nj < 4; ++nj)
                    acc[mi][nj] = __builtin_amdgcn_mfma_f32_16x16x32_bf16(af[mi], bfr[nj], acc[mi][nj], 0, 0, 0);
        }
        __syncthreads();
    }

    // epilogue: C/D layout col = lane&15, row = (lane>>4)*4 + r
    int col = lane & 15, rq = (lane >> 4) * 4;
    #pragma unroll
    for (int mi = 0; mi < 4; ++mi)
        #pragma unroll
        for (int r = 0; r < 4; ++r)
            #pragma unroll
            for (int nj = 0; nj < 4; ++nj)
                SH[(wm + mi * 16 + rq + r) * CSTR + wn + nj * 16 + col] = f2bf(acc[mi][nj][r]);
    __syncthreads();
    bool useNT = (col0 >= ntc0);              // block-uniform: xr half -> nt
    #pragma unroll
    for (int j = 0; j < 8; ++j) {
        int base = (tid + j * 256) * 8;        // idx in 128x128 space
        int r = base >> 7, c = base & 127;
        int gm = row0 + r;
        if (gm < M) {
            if (useNT)
                __builtin_nontemporal_store(*(const uint4v*)&SH[r * CSTR + c],
                                            (uint4v*)&C[(size_t)gm * Nn + col0 + c]);
            else
                *(uint4*)&C[(size_t)gm * Nn + col0 + c] = *(const uint4*)&SH[r * CSTR + c];
        }
    }
}

// ---------------------------------------------------------------------------
// gat (unchanged from R7/R9): 2 waves/node, 2 heads/wave, 16 ch/lane,
// packed-f32 channel math, intra-half butterfly, 2-edge-pair prefetch,
// nt xr loads.
// ---------------------------------------------------------------------------
__global__ __launch_bounds__(128, 4) void gat_aggregate(
    const ushort_t* __restrict__ xl, int xl_stride,
    const ushort_t* __restrict__ xr, int xr_stride,
    const int* __restrict__ offsets, const int* __restrict__ srcs,
    const ushort_t* __restrict__ att, const ushort_t* __restrict__ bias,
    const ushort_t* __restrict__ Wc, const ushort_t* __restrict__ bc,
    float* __restrict__ out, int c0, int Cn, int N, int EN) {
    int bn = blockIdx.x;
    if (bn >= Cn) return;
    int n = c0 + bn;
    int tid = threadIdx.x;
    int w = tid >> 6, lane = tid & 63;
    int h = 2 * w + (lane >> 5);             // this lane's head
    int r = lane & 31;                       // 32 lanes per head
    int hoff = h * FEAT + r * 16;            // 16 channels per lane

    __shared__ float sh[HEADS][FEAT];
    __shared__ float r0s[2], r1s[2];

    f32x2v xrr[8], attr[8];
    { const uint4v* p = (const uint4v*)&xr[(size_t)bn * xr_stride + hoff];
      uint4v qa = __builtin_nontemporal_load(p);          // xr read exactly once
      uint4v qb = __builtin_nontemporal_load(p + 1);
      xrr[0] = up2v(qa.x); xrr[1] = up2v(qa.y); xrr[2] = up2v(qa.z); xrr[3] = up2v(qa.w);
      xrr[4] = up2v(qb.x); xrr[5] = up2v(qb.y); xrr[6] = up2v(qb.z); xrr[7] = up2v(qb.w); }
    { const ushort_t* p = &att[hoff];
      uint4 qa = *(const uint4*)p, qb = *(const uint4*)(p + 8);
      attr[0] = up2v(qa.x); attr[1] = up2v(qa.y); attr[2] = up2v(qa.z); attr[3] = up2v(qa.w);
      attr[4] = up2v(qb.x); attr[5] = up2v(qb.y); attr[6] = up2v(qb.z); attr[7] = up2v(qb.w); }

    int start = offsets[n], end = offsets[n + 1];
    start = max(0, min(start, EN));
    end   = max(start, min(end, EN));
    int deg = end - start;

    int sv = 0;
    if (lane < deg) sv = srcs[start + lane];

    float l = 0.f;
    f32x2v acc[8] = {{0.f,0.f},{0.f,0.f},{0.f,0.f},{0.f,0.f},
                     {0.f,0.f},{0.f,0.f},{0.f,0.f},{0.f,0.f}};
    const ushort_t* xlh = xl + hoff;
    const f32x2v cneg = {NEG - 1.0f, NEG - 1.0f};

    auto getS = [&](int i) -> int {
        if (i >= deg) i = deg - 1;
        if (i < 0) i = 0;
        int s = (i < 64) ? __shfl(sv, i) : srcs[start + i];
        return ((uint)s >= (uint)N) ? 0 : s;
    };
    auto fetchE = [&](int i, uint4& qa, uint4& qb) {
        int s = getS(i);
        const ushort_t* pp = xlh + (size_t)s * xl_stride;
        qa = *(const uint4*)pp;
        qb = *(const uint4*)(pp + 8);
    };
    auto body = [&](uint4 qa, uint4 qb) {
        f32x2v v[8] = {up2v(qa.x), up2v(qa.y), up2v(qa.z), up2v(qa.w),
                       up2v(qb.x), up2v(qb.y), up2v(qb.z), up2v(qb.w)};
        f32x2v p2 = {0.f, 0.f};
        #pragma unroll
        for (int j = 0; j < 8; ++j) {
            f32x2v u  = pk_add(v[j], xrr[j]);
            f32x2v lr = pk_fma(pk_min0(u), cneg, u);   // packed LeakyReLU
            p2 = pk_fma(lr, attr[j], p2);
        }
        float p = p2.x + p2.y;
        #pragma unroll
        for (int off = 16; off >= 1; off >>= 1) p += __shfl_xor(p, off);  // intra-half
        float wgt = __expf(p);
        l += wgt;
        f32x2v wv2; wv2.x = wgt; wv2.y = wgt;
        #pragma unroll
        for (int j = 0; j < 8; ++j) acc[j] = pk_fma(wv2, v[j], acc[j]);
    };

    uint4 a0q, a0r, a1q, a1r, b0q, b0r, b1q, b1r;
    fetchE(0, a0q, a0r);
    fetchE(1, a1q, a1r);
    for (int e = 0; e < deg; e += 2) {
        fetchE(e + 2, b0q, b0r);     // clamped on tail -> L1 hit, discarded
        fetchE(e + 3, b1q, b1r);
        body(a0q, a0r);
        if (e + 1 < deg) body(a1q, a1r);
        a0q = b0q; a0r = b0r; a1q = b1q; a1r = b1r;
    }

    float inv = 0.25f / fmaxf(l, 1e-35f);   // 1/l, mean over heads folded in
    #pragma unroll
    for (int j = 0; j < 8; ++j) {
        sh[h][r * 16 + 2 * j]     = acc[j].x * inv;
        sh[h][r * 16 + 2 * j + 1] = acc[j].y * inv;
    }
    __syncthreads();

    float p0 = 0.f, p1 = 0.f;
    #pragma unroll
    for (int c = tid; c < FEAT; c += 128) {
        float f = sh[0][c] + sh[1][c] + sh[2][c] + sh[3][c] + bf2f(bias[c]);
        uint w2 = *(const uint*)&Wc[c * 2];
        p0 = fmaf(f, bf2f((ushort_t)(w2 & 0xffff)), p0);
        p1 = fmaf(f, bf2f((ushort_t)(w2 >> 16)), p1);
    }
    #pragma unroll
    for (int off = 32; off >= 1; off >>= 1) {
        p0 += __shfl_xor(p0, off);
        p1 += __shfl_xor(p1, off);
    }
    if (lane == 0) { r0s[w] = p0; r1s[w] = p1; }
    __syncthreads();
    if (tid == 0) {
        out[(size_t)n * 2 + 0] = r0s[0] + r0s[1] + bf2f(bc[0]);
        out[(size_t)n * 2 + 1] = r0s[0] * 0.f + r1s[0] + r1s[1] + bf2f(bc[1]);
    }
}

// ---------------------------------------------------------------------------
extern "C" void kernel_launch(void* const* d_in, const int* in_sizes, int n_in,
                              void* d_out, int out_size, void* d_ws, size_t ws_size,
                              hipStream_t stream) {
    const void* x    = d_in[0];
    const int*  ei   = (const int*)d_in[1];
    const void* W_l  = d_in[2];
    const void* W_r  = d_in[3];
    const void* att  = d_in[4];
    const void* bias = d_in[5];
    const void* Wc   = d_in[6];
    const void* bc   = d_in[7];
    float* out = (float*)d_out;

    const int N  = in_sizes[0] / FEAT;     // 20000
    const int E  = in_sizes[1] / 2;        // 160000
    const int K  = FEAT;                   // 512
    const int HC = HEADS * FEAT;           // 2048
    const int EN = E + N;
    const int Nb = (N + 1023) / 1024;

    const int* src = ei;
    const int* dst = ei + E;

    // ---- adaptive workspace layout ----
    char* base = (char*)d_ws;
    size_t off = 0;
    auto alloc = [&](size_t bytes) -> char* {
        char* p = base + off;
        off = (off + bytes + 255) & ~(size_t)255;
        return p;
    };
    int* flag    = (int*)alloc(4);
    int* offsets = (int*)alloc((size_t)(N + 1) * 4);
    int* cursor  = (int*)alloc((size_t)N * 4);
    int* deg     = (int*)alloc((size_t)N * 4);
    int* part    = (int*)alloc((size_t)N * 4);
    int* bsum    = (int*)alloc((size_t)(Nb + 1) * 4);
    int* srcs    = (int*)alloc((size_t)EN * 4);
    ushort_t* attc  = (ushort_t*)alloc((size_t)HC * 2);
    ushort_t* biasc = (ushort_t*)alloc((size_t)FEAT * 2);
    ushort_t* Wcc   = (ushort_t*)alloc((size_t)FEAT * 2 * 2);
    ushort_t* bcc   = (ushort_t*)alloc(2 * 2);
    ushort_t* xc   = (ushort_t*)alloc((size_t)N * K * 2);
    ushort_t* Wcat = (ushort_t*)alloc((size_t)2 * HC * K * 2);   // [Wl^T ; Wr^T]
    size_t fixed = off;

    size_t need_merged = (size_t)N * 2 * HC * 2;
    bool merged = (ws_size >= fixed + need_merged);

    long long NX = (long long)N * K;

    if (N <= 24576) {
        // 0) ONE mega dispatch: CSR-in-LDS + flag/small canon + W transpose + x canon
        int nT4b = ((HC / 64) * (K / 64) * 2 + 3) / 4;       // 128
        int nxb1k = (int)((NX + 8191) / 8192);               // 1250
        mega_kernel<<<2 + nT4b + nxb1k, 1024, 0, stream>>>(
            (const ushort_t*)x, flag, dst, offsets, cursor, N, E,
            att, attc, HC, bias, biasc, FEAT, Wc, Wcc, FEAT * 2, bc, bcc, 2,
            W_l, W_r, Wcat, Wcat + (size_t)HC * K, K, HC, nT4b,
            x, xc, NX);
    } else {
        // fallback preamble (4 dispatches)
        const int NBZ = (N + 1023) / 1024;
        const int nT = (HC / 64) * (K / 64) * 2;
        prep_kernel<<<NBZ + 15 + nT, 256, 0, stream>>>(
            (const ushort_t*)x, flag, deg, N, NBZ,
            att, attc, HC, bias, biasc, FEAT, Wc, Wcc, FEAT * 2, bc, bcc, 2,
            W_l, W_r, Wcat, Wcat + (size_t)HC * K, K, HC);
        const int NH = (E + 255) / 256;
        int nxb = (int)((NX / 8 + 255) / 256);
        histx_kernel<<<NH + nxb, 256, 0, stream>>>(
            (const ushort_t*)x, dst, deg, E, NH, N, x, xc, NX);
        scan1<<<Nb, 256, 0, stream>>>(deg, part, bsum, N);
        scan3<<<Nb, 256, 0, stream>>>(part, bsum, offsets, cursor, N, Nb);
    }

    const ushort_t* x_bf = (const ushort_t*)x;
    const int nScB = (EN + 255) / 256;

    if (merged) {
        ushort_t* xlr = (ushort_t*)(base + fixed);       // N x 4096: [xl | xr]
        int gx = 2 * HC / 128;                           // 32
        int gyG = (N + 127) / 128;                       // 157
        int exR = (nScB + gx - 1) / gx;                  // 22 scatter rows
        dim3 gg(gx, gyG + exR);
        // nt-store the xr half (cols >= HC): single-use stream, keep xl in L3
        gemm128<<<gg, 256, 0, stream>>>(x_bf, xc, flag, Wcat, xlr, N, 2 * HC, K,
                                        HC, gyG, src, dst, cursor, srcs, E, N, nScB);
        gat_aggregate<<<N, 128, 0, stream>>>(xlr, 2 * HC, xlr + HC, 2 * HC,
                                             offsets, srcs, attc, biasc, Wcc, bcc,
                                             out, 0, N, N, EN);
    } else {
        scatter_kernel<<<nScB, 256, 0, stream>>>(src, dst, cursor, srcs, E, N);
        ushort_t* xl = (ushort_t*)alloc((size_t)N * HC * 2);
        size_t remain = (ws_size > off) ? (ws_size - off) : 0;
        long long Cmax = (long long)(remain / ((size_t)HC * 2));
        int C = (Cmax >= N) ? N : (int)(Cmax & ~63LL);
        if (C < 64) C = 64;
        ushort_t* xrc = (ushort_t*)(base + off);
        ushort_t* Wlt = Wcat;
        ushort_t* Wrt = Wcat + (size_t)HC * K;

        dim3 gl(HC / 128, (N + 127) / 128);
        gemm128<<<gl, 256, 0, stream>>>(x_bf, xc, flag, Wlt, xl, N, HC, K,
                                        HC /*no nt: all xl*/, (N + 127) / 128,
                                        nullptr, nullptr, nullptr, nullptr, 0, 0, 0);
        for (int c0 = 0; c0 < N; c0 += C) {
            int Cn = (N - c0 < C) ? (N - c0) : C;
            dim3 gr(HC / 128, (Cn + 127) / 128);
            gemm128<<<gr, 256, 0, stream>>>(x_bf + (size_t)c0 * K, xc + (size_t)c0 * K, flag,
                                            Wrt, xrc, Cn, HC, K,
                                            0 /*all nt: xr stream*/, (Cn + 127) / 128,
                                            nullptr, nullptr, nullptr, nullptr, 0, 0, 0);
            gat_aggregate<<<Cn, 128, 0, stream>>>(xl, HC, xrc, HC,
                                                  offsets, srcs, attc, biasc, Wcc, bcc,
                                                  out, c0, Cn, N, EN);
        }
    }
}

// Round 11
// 325.011 us; speedup vs baseline: 1.0137x; 1.0137x over previous
//
#include <hip/hip_runtime.h>
#include <hip/hip_bf16.h>

#define FEAT    512
#define HEADS   4
#define NEG     0.2f

typedef unsigned int uint;
typedef unsigned short ushort_t;
typedef __attribute__((ext_vector_type(8))) short bf16x8v;   // 8 bf16 = 4 VGPRs
typedef __attribute__((ext_vector_type(4))) float f32x4v;    // mfma acc
typedef __attribute__((ext_vector_type(2))) float f32x2v;    // packed-f32 pair
typedef __attribute__((ext_vector_type(4))) uint uint4v;     // nt-load-able 16B
typedef __attribute__((address_space(3))) uint lds_u32_t;
typedef __attribute__((address_space(1))) const uint g_u32_t;

__device__ inline float bf2f(ushort_t h) { return __uint_as_float(((uint)h) << 16); }
__device__ inline ushort_t f2bf(float f) {
    uint u = __float_as_uint(f);
    u += 0x7fff + ((u >> 16) & 1);           // RNE
    return (ushort_t)(u >> 16);
}
// packed-f32 VOP3P ops (1 inst / 2 lanes).
__device__ inline f32x2v pk_add(f32x2v a, f32x2v b) {
    f32x2v d; asm("v_pk_add_f32 %0, %1, %2" : "=v"(d) : "v"(a), "v"(b)); return d;
}
__device__ inline f32x2v pk_fma(f32x2v a, f32x2v b, f32x2v c) {
    f32x2v d; asm("v_pk_fma_f32 %0, %1, %2, %3" : "=v"(d) : "v"(a), "v"(b), "v"(c)); return d;
}
__device__ inline f32x2v up2v(uint d) {      // 2 packed bf16 -> f32x2v, 2 inst
    f32x2v r; r.x = __uint_as_float(d << 16); r.y = __uint_as_float(d & 0xffff0000u); return r;
}
__device__ inline f32x2v pk_min0(f32x2v a) { // no v_pk_min_f32 -> 2 scalar mins
    f32x2v r; r.x = fminf(a.x, 0.f); r.y = fminf(a.y, 0.f); return r;
}

// ---------------------------------------------------------------------------
// prep (R7 config): dtype probe + deg zeroing + small-array canon + BOTH
// weight transposes. block roles: [0,NBZ) zero deg | [NBZ,NBZ+15) small4 |
// rest W transpose.
// ---------------------------------------------------------------------------
__global__ __launch_bounds__(256) void prep_kernel(
    const ushort_t* __restrict__ xprobe, int* flag,
    int* __restrict__ deg, int N, int NBZ,
    const void* a0, ushort_t* o0, int n0, const void* a1, ushort_t* o1, int n1,
    const void* a2, ushort_t* o2, int n2, const void* a3, ushort_t* o3, int n3,
    const void* __restrict__ Wl, const void* __restrict__ Wr,
    ushort_t* __restrict__ WtL, ushort_t* __restrict__ WtR, int Kk, int HCk) {
    __shared__ int s_isbf;
    __shared__ ushort_t t[64][72];
    int tid = threadIdx.x;
    if (tid < 64) {
        int hits = 0;
        for (int i = tid; i < 128; i += 64) {
            ushort_t w = xprobe[2 * i];
            uint hb = (w >> 8) & 0x7f;
            hits += (hb >= 0x38 && hb <= 0x42) ? 1 : 0;
        }
        #pragma unroll
        for (int off = 32; off >= 1; off >>= 1) hits += __shfl_xor(hits, off);
        if (tid == 0) s_isbf = (hits >= 64) ? 1 : 0;
    }
    __syncthreads();
    int isbf = s_isbf;
    int b = blockIdx.x;
    if (b == 0 && tid == 0) *flag = isbf;

    if (b < NBZ) {                       // zero deg (int4)
        int i0 = (b * 256 + tid) * 4;
        if (i0 + 4 <= N) *(int4*)&deg[i0] = make_int4(0, 0, 0, 0);
        else for (int j = 0; j < 4; ++j) if (i0 + j < N) deg[i0 + j] = 0;
        return;
    }
    if (b < NBZ + 15) {                  // canon small4
        int idx = (b - NBZ) * 256 + tid;
        const void* srcs[4] = {a0, a1, a2, a3};
        ushort_t* dsts[4] = {o0, o1, o2, o3};
        int ns[4] = {n0, n1, n2, n3};
        #pragma unroll
        for (int k = 0; k < 4; ++k) {
            if (idx < ns[k]) {
                dsts[k][idx] = isbf ? ((const ushort_t*)srcs[k])[idx]
                                    : f2bf(((const float*)srcs[k])[idx]);
                return;
            }
            idx -= ns[k];
        }
        return;
    }
    // W transpose+canon: out[HC][K] = in[K][HC]
    int b2 = b - (NBZ + 15);
    int z = b2 & 1;
    int rest = b2 >> 1;
    int ntk = Kk >> 6;                   // K/64 tiles
    int ky = rest % ntk, nxt = rest / ntk;
    const void* in = z ? Wr : Wl;
    ushort_t* outp = z ? WtR : WtL;
    int kt0 = ky * 64, nt0 = nxt * 64;
    int r = tid >> 3;                    // 0..31
    int c = (tid & 7) * 8;               // 0,8,..,56
    #pragma unroll
    for (int p = 0; p < 2; ++p) {
        int row = r + p * 32;
        size_t base = (size_t)(kt0 + row) * HCk + nt0 + c;
        if (isbf) {
            *(uint4*)&t[row][c] = *(const uint4*)((const ushort_t*)in + base);
        } else {
            const float* f = (const float*)in + base;
            float4 a = *(const float4*)f, bb = *(const float4*)(f + 4);
            ushort_t o[8] = {f2bf(a.x), f2bf(a.y), f2bf(a.z), f2bf(a.w),
                             f2bf(bb.x), f2bf(bb.y), f2bf(bb.z), f2bf(bb.w)};
            *(uint4*)&t[row][c] = *(uint4*)o;
        }
    }
    __syncthreads();
    #pragma unroll
    for (int p = 0; p < 2; ++p) {
        int row = r + p * 32;
        #pragma unroll
        for (int j = 0; j < 8; ++j)
            outp[(size_t)(nt0 + row) * Kk + kt0 + c + j] = t[c + j][row];
    }
}

// ---------------------------------------------------------------------------
// hist + x canon fused: [0,NH) hist atomics | rest: x fp32->bf16 canon.
// ---------------------------------------------------------------------------
__global__ __launch_bounds__(256) void histx_kernel(
    const ushort_t* __restrict__ xprobe,
    const int* __restrict__ dstE, int* deg, int E, int NH, int Ngr,
    const void* __restrict__ xin, ushort_t* __restrict__ xc, long long nx) {
    int tid = threadIdx.x;
    int b = blockIdx.x;
    if (b < NH) {                        // hist
        int i = b * 256 + tid;
        if (i < E) {
            int d = dstE[i];
            if ((uint)d < (uint)Ngr) atomicAdd(&deg[d], 1);
        }
        return;
    }
    __shared__ int s_isbf;
    if (tid < 64) {
        int hits = 0;
        for (int i = tid; i < 128; i += 64) {
            ushort_t w = xprobe[2 * i];
            uint hb = (w >> 8) & 0x7f;
            hits += (hb >= 0x38 && hb <= 0x42) ? 1 : 0;
        }
        #pragma unroll
        for (int off = 32; off >= 1; off >>= 1) hits += __shfl_xor(hits, off);
        if (tid == 0) s_isbf = (hits >= 64) ? 1 : 0;
    }
    __syncthreads();
    if (s_isbf) return;                  // x used directly when already bf16
    long long i0 = ((long long)(b - NH) * 256 + tid) * 8;
    if (i0 + 8 <= nx) {
        const float* f = (const float*)xin + i0;
        float4 a = *(const float4*)f, bb = *(const float4*)(f + 4);
        ushort_t o[8] = {f2bf(a.x), f2bf(a.y), f2bf(a.z), f2bf(a.w),
                         f2bf(bb.x), f2bf(bb.y), f2bf(bb.z), f2bf(bb.w)};
        *(uint4*)&xc[i0] = *(uint4*)o;
    } else {
        for (long long i = i0; i < nx; ++i) xc[i] = f2bf(((const float*)xin)[i]);
    }
}

// phase 1: per-1024-block exclusive scan over (deg[i] + 1)  [+1 = self-loop]
__global__ __launch_bounds__(256) void scan1(const int* __restrict__ deg, int* __restrict__ part,
                                             int* __restrict__ bsum, int N) {
    __shared__ int tmp[256];
    int b = blockIdx.x, tid = threadIdx.x;
    int i0 = b * 1024 + tid * 4;
    int v[4] = {0, 0, 0, 0};
    if (i0 + 4 <= N) { int4 q = *(const int4*)&deg[i0]; v[0]=q.x+1; v[1]=q.y+1; v[2]=q.z+1; v[3]=q.w+1; }
    else { for (int j = 0; j < 4; ++j) v[j] = (i0 + j < N) ? deg[i0 + j] + 1 : 0; }
    int s0 = v[0], s1 = s0 + v[1], s2 = s1 + v[2], s3 = s2 + v[3];
    tmp[tid] = s3;
    __syncthreads();
    for (int off = 1; off < 256; off <<= 1) {
        int t = (tid >= off) ? tmp[tid - off] : 0;
        __syncthreads();
        tmp[tid] += t;
        __syncthreads();
    }
    int base = tid ? tmp[tid - 1] : 0;
    int e[4] = {base, base + s0, base + s1, base + s2};
    if (i0 + 4 <= N) { *(int4*)&part[i0] = make_int4(e[0], e[1], e[2], e[3]); }
    else { for (int j = 0; j < 4; ++j) if (i0 + j < N) part[i0 + j] = e[j]; }
    if (tid == 255) bsum[b] = tmp[255];
}

// phase 2 (fused): each block wave-scans the Nb block sums itself (Nb <= 64)
__global__ __launch_bounds__(256) void scan3(const int* __restrict__ part, const int* __restrict__ bsum,
                                             int* __restrict__ offsets, int* __restrict__ cursor,
                                             int N, int Nb) {
    __shared__ int s_add, s_tot;
    int b = blockIdx.x, tid = threadIdx.x;
    if (tid < 64) {
        int v = (tid < Nb) ? bsum[tid] : 0;
        int incl = v;
        #pragma unroll
        for (int off = 1; off < 64; off <<= 1) {
            int t = __shfl_up(incl, off);
            if (tid >= off) incl += t;
        }
        if (tid == b) s_add = incl - v;
        if (tid == Nb - 1) s_tot = incl;
    }
    __syncthreads();
    int add = s_add;
    int i0 = b * 1024 + tid * 4;
    #pragma unroll
    for (int j = 0; j < 4; ++j) {
        int i = i0 + j;
        if (i < N) { int o = part[i] + add; offsets[i] = o; cursor[i] = o; }
    }
    if (b == Nb - 1 && tid == 0) offsets[N] = s_tot;   // = E + N
}

__global__ void scatter_kernel(const int* __restrict__ src, const int* __restrict__ dst,
                               int* cursor, int* srcs, int E, int N) {
    int i = blockIdx.x * blockDim.x + threadIdx.x;
    if (i >= E + N) return;
    int s, d;
    if (i < E) { s = src[i]; d = dst[i]; }
    else       { s = i - E; d = i - E; }   // self-loop
    if ((uint)d >= (uint)N) return;
    int pos = atomicAdd(&cursor[d], 1);
    if ((uint)pos < (uint)(E + N)) srcs[pos] = s;
}

// ---------------------------------------------------------------------------
// MFMA bf16 GEMM (+ fused scatter rows). C[M,N] = A[M,K] @ Bt[N,K]^T.
// 128x128 tile, 4 waves of 64x64, BK=64. Proven ~115us on this shape.
// (R10's nt-store on the xr half: REFUTED — gat FETCH_SIZE byte-identical
// 385MB, total regressed. Plain stores restored.)
// ---------------------------------------------------------------------------
__global__ __launch_bounds__(256) void gemm128(const ushort_t* A_bf, const ushort_t* A_cv,
                                               const int* __restrict__ flag,
                                               const ushort_t* __restrict__ Bt,
                                               ushort_t* __restrict__ C,
                                               int M, int Nn, int K, int gyGemm,
                                               const int* __restrict__ esrc,
                                               const int* __restrict__ edst,
                                               int* cursor, int* srcsOut,
                                               int E, int Ngr, int nScB) {
    if ((int)blockIdx.y >= gyGemm) {       // scatter role
        int id = ((int)blockIdx.y - gyGemm) * (int)gridDim.x + (int)blockIdx.x;
        if (id < nScB) {
            int i = id * 256 + (int)threadIdx.x;
            int EN = E + Ngr;
            if (i < EN) {
                int s, d;
                if (i < E) { s = esrc[i]; d = edst[i]; }
                else       { s = i - E; d = i - E; }   // self-loop
                if ((uint)d < (uint)Ngr) {
                    int pos = atomicAdd(&cursor[d], 1);
                    if ((uint)pos < (uint)EN) srcsOut[pos] = s;
                }
            }
        }
        return;
    }
    constexpr int CSTR = 132;                 // epilogue row stride (bank spread)
    __shared__ ushort_t SH[128 * CSTR];       // 33792 B; staging uses first 32KB
    ushort_t* As = SH;                        // As[2][4096]
    ushort_t* Bs = SH + 8192;                 // Bs[2][4096]
    const ushort_t* A = (*flag) ? A_bf : A_cv;
    int tid = threadIdx.x;
    int wave = tid >> 6, lane = tid & 63;
    int row0 = blockIdx.y * 128, col0 = blockIdx.x * 128;
    int wm = (wave >> 1) * 64, wn = (wave & 1) * 64;

    f32x4v acc[4][4];
    #pragma unroll
    for (int i = 0; i < 4; ++i)
        #pragma unroll
        for (int j = 0; j < 4; ++j) acc[i][j] = (f32x4v){0.f, 0.f, 0.f, 0.f};

    int fm = lane & 15, kq8 = (lane >> 4) * 8;

    // staging (coalesced 64B runs): chunk p -> row=p>>2, kp=p&3
    const ushort_t* srcA[2]; ushort_t* dstA0[2]; ushort_t* dstA1[2];
    const ushort_t* srcB[2]; ushort_t* dstB0[2]; ushort_t* dstB1[2];
    #pragma unroll
    for (int i = 0; i < 2; ++i) {
        int p = (wave * 2 + i) * 64 + lane;
        int row = p >> 2, kp = p & 3;
        int gra = row0 + row; if (gra >= M) gra = M - 1;   // tail clamp (C-write guarded)
        srcA[i] = &A[(size_t)gra * K + kp * 8];
        srcB[i] = &Bt[(size_t)(col0 + row) * K + kp * 8];
        dstA0[i] = &As[p * 8]; dstA1[i] = &As[4096 + p * 8];
        dstB0[i] = &Bs[p * 8]; dstB1[i] = &Bs[4096 + p * 8];
    }

    for (int k0 = 0; k0 < K; k0 += 64) {
        #pragma unroll
        for (int i = 0; i < 2; ++i) {
            __builtin_amdgcn_global_load_lds((g_u32_t*)srcA[i],        (lds_u32_t*)dstA0[i], 16, 0, 0);
            __builtin_amdgcn_global_load_lds((g_u32_t*)(srcA[i] + 32), (lds_u32_t*)dstA1[i], 16, 0, 0);
            __builtin_amdgcn_global_load_lds((g_u32_t*)srcB[i],        (lds_u32_t*)dstB0[i], 16, 0, 0);
            __builtin_amdgcn_global_load_lds((g_u32_t*)(srcB[i] + 32), (lds_u32_t*)dstB1[i], 16, 0, 0);
            srcA[i] += 64; srcB[i] += 64;
        }
        __syncthreads();

        #pragma unroll
        for (int panel = 0; panel < 2; ++panel) {
            bf16x8v af[4], bfr[4];
            #pragma unroll
            for (int mi = 0; mi < 4; ++mi)
                af[mi] = *(const bf16x8v*)&As[panel * 4096 + (wm + mi * 16 + fm) * 32 + kq8];
            #pragma unroll
            for (int nj = 0; nj < 4; ++nj)
                bfr[nj] = *(const bf16x8v*)&Bs[panel * 4096 + (wn + nj * 16 + fm) * 32 + kq8];
            #pragma unroll
            for (int mi = 0; mi < 4; ++mi)
                #pragma unroll
                for (int nj = 0; nj < 4; ++nj)
                    acc[mi][nj] = __builtin_amdgcn_mfma_f32_16x16x32_bf16(af[mi], bfr[nj], acc[mi][nj], 0, 0, 0);
        }
        __syncthreads();
    }

    // epilogue: C/D layout col = lane&15, row = (lane>>4)*4 + r
    int col = lane & 15, rq = (lane >> 4) * 4;
    #pragma unroll
    for (int mi = 0; mi < 4; ++mi)
        #pragma unroll
        for (int r = 0; r < 4; ++r)
            #pragma unroll
            for (int nj = 0; nj < 4; ++nj)
                SH[(wm + mi * 16 + rq + r) * CSTR + wn + nj * 16 + col] = f2bf(acc[mi][nj][r]);
    __syncthreads();
    #pragma unroll
    for (int j = 0; j < 8; ++j) {
        int base = (tid + j * 256) * 8;        // idx in 128x128 space
        int r = base >> 7, c = base & 127;
        int gm = row0 + r;
        if (gm < M)
            *(uint4*)&C[(size_t)gm * Nn + col0 + c] = *(const uint4*)&SH[r * CSTR + c];
    }
}

// ---------------------------------------------------------------------------
// gat (R11): R7 structure + prefetch depth 2->4 edges (3 pairs live).
// Rationale: R7/R9 counters show VALUBusy 65% + HBM 42% — neither saturated,
// ~30us of gather-stall. With 1-pair-ahead prefetch, the ~500cyc VALU body
// covers L2-hit latency (~200cyc) but not the ~900cyc HBM misses that half
// the gathers take (FETCH 385MB of 737MB logical). 3 live pairs = 6 rows
// outstanding covers HBM-miss latency under 2 bodies. +16 VGPR (60->~76).
// Layout unchanged: 2 waves/node, 2 heads/wave, 16 ch/lane, packed-f32
// channel math, intra-half butterfly, nt xr loads. OUTPUT FP32.
// ---------------------------------------------------------------------------
__global__ __launch_bounds__(128, 4) void gat_aggregate(
    const ushort_t* __restrict__ xl, int xl_stride,
    const ushort_t* __restrict__ xr, int xr_stride,
    const int* __restrict__ offsets, const int* __restrict__ srcs,
    const ushort_t* __restrict__ att, const ushort_t* __restrict__ bias,
    const ushort_t* __restrict__ Wc, const ushort_t* __restrict__ bc,
    float* __restrict__ out, int c0, int Cn, int N, int EN) {
    int bn = blockIdx.x;
    if (bn >= Cn) return;
    int n = c0 + bn;
    int tid = threadIdx.x;
    int w = tid >> 6, lane = tid & 63;
    int h = 2 * w + (lane >> 5);             // this lane's head
    int r = lane & 31;                       // 32 lanes per head
    int hoff = h * FEAT + r * 16;            // 16 channels per lane

    __shared__ float sh[HEADS][FEAT];
    __shared__ float r0s[2], r1s[2];

    f32x2v xrr[8], attr[8];
    { const uint4v* p = (const uint4v*)&xr[(size_t)bn * xr_stride + hoff];
      uint4v qa = __builtin_nontemporal_load(p);          // xr read exactly once
      uint4v qb = __builtin_nontemporal_load(p + 1);
      xrr[0] = up2v(qa.x); xrr[1] = up2v(qa.y); xrr[2] = up2v(qa.z); xrr[3] = up2v(qa.w);
      xrr[4] = up2v(qb.x); xrr[5] = up2v(qb.y); xrr[6] = up2v(qb.z); xrr[7] = up2v(qb.w); }
    { const ushort_t* p = &att[hoff];
      uint4 qa = *(const uint4*)p, qb = *(const uint4*)(p + 8);
      attr[0] = up2v(qa.x); attr[1] = up2v(qa.y); attr[2] = up2v(qa.z); attr[3] = up2v(qa.w);
      attr[4] = up2v(qb.x); attr[5] = up2v(qb.y); attr[6] = up2v(qb.z); attr[7] = up2v(qb.w); }

    int start = offsets[n], end = offsets[n + 1];
    start = max(0, min(start, EN));
    end   = max(start, min(end, EN));
    int deg = end - start;

    int sv = 0;
    if (lane < deg) sv = srcs[start + lane];

    float l = 0.f;
    f32x2v acc[8] = {{0.f,0.f},{0.f,0.f},{0.f,0.f},{0.f,0.f},
                     {0.f,0.f},{0.f,0.f},{0.f,0.f},{0.f,0.f}};
    const ushort_t* xlh = xl + hoff;
    const f32x2v cneg = {NEG - 1.0f, NEG - 1.0f};

    auto getS = [&](int i) -> int {
        if (i >= deg) i = deg - 1;
        if (i < 0) i = 0;
        int s = (i < 64) ? __shfl(sv, i) : srcs[start + i];
        return ((uint)s >= (uint)N) ? 0 : s;
    };
    auto fetchE = [&](int i, uint4& qa, uint4& qb) {
        int s = getS(i);
        const ushort_t* pp = xlh + (size_t)s * xl_stride;
        qa = *(const uint4*)pp;
        qb = *(const uint4*)(pp + 8);
    };
    auto body = [&](uint4 qa, uint4 qb) {
        f32x2v v[8] = {up2v(qa.x), up2v(qa.y), up2v(qa.z), up2v(qa.w),
                       up2v(qb.x), up2v(qb.y), up2v(qb.z), up2v(qb.w)};
        f32x2v p2 = {0.f, 0.f};
        #pragma unroll
        for (int j = 0; j < 8; ++j) {
            f32x2v u  = pk_add(v[j], xrr[j]);
            f32x2v lr = pk_fma(pk_min0(u), cneg, u);   // packed LeakyReLU
            p2 = pk_fma(lr, attr[j], p2);
        }
        float p = p2.x + p2.y;
        #pragma unroll
        for (int off = 16; off >= 1; off >>= 1) p += __shfl_xor(p, off);  // intra-half
        float wgt = __expf(p);
        l += wgt;
        f32x2v wv2; wv2.x = wgt; wv2.y = wgt;
        #pragma unroll
        for (int j = 0; j < 8; ++j) acc[j] = pk_fma(wv2, v[j], acc[j]);
    };

    // 3-pair pipeline: pairs A=(e,e+1) in body, B=(e+2,e+3) landed,
    // C=(e+4,e+5) issuing. Tail over-fetches are index-clamped -> L1 hits.
    uint4 a0q, a0r, a1q, a1r, b0q, b0r, b1q, b1r, c0q, c0r, c1q, c1r;
    fetchE(0, a0q, a0r);
    fetchE(1, a1q, a1r);
    fetchE(2, b0q, b0r);
    fetchE(3, b1q, b1r);
    for (int e = 0; e < deg; e += 2) {
        fetchE(e + 4, c0q, c0r);
        fetchE(e + 5, c1q, c1r);
        body(a0q, a0r);
        if (e + 1 < deg) body(a1q, a1r);
        a0q = b0q; a0r = b0r; a1q = b1q; a1r = b1r;
        b0q = c0q; b0r = c0r; b1q = c1q; b1r = c1r;
    }

    float inv = 0.25f / fmaxf(l, 1e-35f);   // 1/l, mean over heads folded in
    #pragma unroll
    for (int j = 0; j < 8; ++j) {
        sh[h][r * 16 + 2 * j]     = acc[j].x * inv;
        sh[h][r * 16 + 2 * j + 1] = acc[j].y * inv;
    }
    __syncthreads();

    float p0 = 0.f, p1 = 0.f;
    #pragma unroll
    for (int c = tid; c < FEAT; c += 128) {
        float f = sh[0][c] + sh[1][c] + sh[2][c] + sh[3][c] + bf2f(bias[c]);
        uint w2 = *(const uint*)&Wc[c * 2];
        p0 = fmaf(f, bf2f((ushort_t)(w2 & 0xffff)), p0);
        p1 = fmaf(f, bf2f((ushort_t)(w2 >> 16)), p1);
    }
    #pragma unroll
    for (int off = 32; off >= 1; off >>= 1) {
        p0 += __shfl_xor(p0, off);
        p1 += __shfl_xor(p1, off);
    }
    if (lane == 0) { r0s[w] = p0; r1s[w] = p1; }
    __syncthreads();
    if (tid == 0) {
        out[(size_t)n * 2 + 0] = r0s[0] + r0s[1] + bf2f(bc[0]);
        out[(size_t)n * 2 + 1] = r1s[0] + r1s[1] + bf2f(bc[1]);
    }
}

// ---------------------------------------------------------------------------
extern "C" void kernel_launch(void* const* d_in, const int* in_sizes, int n_in,
                              void* d_out, int out_size, void* d_ws, size_t ws_size,
                              hipStream_t stream) {
    const void* x    = d_in[0];
    const int*  ei   = (const int*)d_in[1];
    const void* W_l  = d_in[2];
    const void* W_r  = d_in[3];
    const void* att  = d_in[4];
    const void* bias = d_in[5];
    const void* Wc   = d_in[6];
    const void* bc   = d_in[7];
    float* out = (float*)d_out;

    const int N  = in_sizes[0] / FEAT;     // 20000
    const int E  = in_sizes[1] / 2;        // 160000
    const int K  = FEAT;                   // 512
    const int HC = HEADS * FEAT;           // 2048
    const int EN = E + N;
    const int Nb = (N + 1023) / 1024;      // scan blocks (20 <= 64)

    const int* src = ei;
    const int* dst = ei + E;

    // ---- adaptive workspace layout ----
    char* base = (char*)d_ws;
    size_t off = 0;
    auto alloc = [&](size_t bytes) -> char* {
        char* p = base + off;
        off = (off + bytes + 255) & ~(size_t)255;
        return p;
    };
    int* flag    = (int*)alloc(4);
    int* offsets = (int*)alloc((size_t)(N + 1) * 4);
    int* cursor  = (int*)alloc((size_t)N * 4);
    int* deg     = (int*)alloc((size_t)N * 4);
    int* part    = (int*)alloc((size_t)N * 4);
    int* bsum    = (int*)alloc((size_t)(Nb + 1) * 4);
    int* srcs    = (int*)alloc((size_t)EN * 4);
    ushort_t* attc  = (ushort_t*)alloc((size_t)HC * 2);
    ushort_t* biasc = (ushort_t*)alloc((size_t)FEAT * 2);
    ushort_t* Wcc   = (ushort_t*)alloc((size_t)FEAT * 2 * 2);
    ushort_t* bcc   = (ushort_t*)alloc(2 * 2);
    ushort_t* xc   = (ushort_t*)alloc((size_t)N * K * 2);
    ushort_t* Wcat = (ushort_t*)alloc((size_t)2 * HC * K * 2);   // [Wl^T ; Wr^T]
    size_t fixed = off;

    size_t need_merged = (size_t)N * 2 * HC * 2;
    bool merged = (ws_size >= fixed + need_merged);

    // 0) prep: probe + deg-zero + small canon + W transpose
    long long NX = (long long)N * K;
    const int NBZ = (N + 1023) / 1024;                       // deg-zero blocks
    const int nT = (HC / 64) * (K / 64) * 2;                 // 512 transpose blocks
    prep_kernel<<<NBZ + 15 + nT, 256, 0, stream>>>(
        (const ushort_t*)x, flag, deg, N, NBZ,
        att, attc, HC, bias, biasc, FEAT, Wc, Wcc, FEAT * 2, bc, bcc, 2,
        W_l, W_r, Wcat, Wcat + (size_t)HC * K, K, HC);

    // 1) hist + x canon fused (both depend only on prep)
    const int NH = (E + 255) / 256;
    int nxb = (int)((NX / 8 + 255) / 256);
    histx_kernel<<<NH + nxb, 256, 0, stream>>>(
        (const ushort_t*)x, dst, deg, E, NH, N, x, xc, NX);

    // 2) scans
    scan1<<<Nb, 256, 0, stream>>>(deg, part, bsum, N);
    scan3<<<Nb, 256, 0, stream>>>(part, bsum, offsets, cursor, N, Nb);

    const ushort_t* x_bf = (const ushort_t*)x;
    const int nScB = (EN + 255) / 256;                       // scatter blocks

    if (merged) {
        ushort_t* xlr = (ushort_t*)(base + fixed);       // N x 4096: [xl | xr]
        int gx = 2 * HC / 128;                           // 32
        int gyG = (N + 127) / 128;                       // 157
        int exR = (nScB + gx - 1) / gx;                  // 22 scatter rows
        dim3 gg(gx, gyG + exR);
        // 3) gemm + fused scatter (scatter needs only scan3; overlaps gemm)
        gemm128<<<gg, 256, 0, stream>>>(x_bf, xc, flag, Wcat, xlr, N, 2 * HC, K,
                                        gyG, src, dst, cursor, srcs, E, N, nScB);
        // 4) gat
        gat_aggregate<<<N, 128, 0, stream>>>(xlr, 2 * HC, xlr + HC, 2 * HC,
                                             offsets, srcs, attc, biasc, Wcc, bcc,
                                             out, 0, N, N, EN);
    } else {
        // fallback: separate scatter + xl + chunked xr
        scatter_kernel<<<nScB, 256, 0, stream>>>(src, dst, cursor, srcs, E, N);
        ushort_t* xl = (ushort_t*)alloc((size_t)N * HC * 2);
        size_t remain = (ws_size > off) ? (ws_size - off) : 0;
        long long Cmax = (long long)(remain / ((size_t)HC * 2));
        int C = (Cmax >= N) ? N : (int)(Cmax & ~63LL);
        if (C < 64) C = 64;
        ushort_t* xrc = (ushort_t*)(base + off);
        ushort_t* Wlt = Wcat;
        ushort_t* Wrt = Wcat + (size_t)HC * K;

        dim3 gl(HC / 128, (N + 127) / 128);
        gemm128<<<gl, 256, 0, stream>>>(x_bf, xc, flag, Wlt, xl, N, HC, K,
                                        (N + 127) / 128, nullptr, nullptr,
                                        nullptr, nullptr, 0, 0, 0);
        for (int c0 = 0; c0 < N; c0 += C) {
            int Cn = (N - c0 < C) ? (N - c0) : C;
            dim3 gr(HC / 128, (Cn + 127) / 128);
            gemm128<<<gr, 256, 0, stream>>>(x_bf + (size_t)c0 * K, xc + (size_t)c0 * K, flag,
                                            Wrt, xrc, Cn, HC, K,
                                            (Cn + 127) / 128, nullptr, nullptr,
                                            nullptr, nullptr, 0, 0, 0);
            gat_aggregate<<<Cn, 128, 0, stream>>>(xl, HC, xrc, HC,
                                                  offsets, srcs, attc, biasc, Wcc, bcc,
                                                  out, c0, Cn, N, EN);
        }
    }
}

// Round 12
// 322.514 us; speedup vs baseline: 1.0215x; 1.0077x over previous
//
#include <hip/hip_runtime.h>
#include <hip/hip_bf16.h>

#define FEAT    512
#define HEADS   4
#define NEG     0.2f

typedef unsigned int uint;
typedef unsigned short ushort_t;
typedef __attribute__((ext_vector_type(8))) short bf16x8v;   // 8 bf16 = 4 VGPRs
typedef __attribute__((ext_vector_type(4))) float f32x4v;    // mfma acc
typedef __attribute__((ext_vector_type(2))) float f32x2v;    // packed-f32 pair
typedef __attribute__((ext_vector_type(4))) uint uint4v;     // nt-load-able 16B
typedef __attribute__((address_space(3))) uint lds_u32_t;
typedef __attribute__((address_space(1))) const uint g_u32_t;

__device__ inline float bf2f(ushort_t h) { return __uint_as_float(((uint)h) << 16); }
__device__ inline ushort_t f2bf(float f) {
    uint u = __float_as_uint(f);
    u += 0x7fff + ((u >> 16) & 1);           // RNE
    return (ushort_t)(u >> 16);
}
// packed-f32 VOP3P ops (1 inst / 2 lanes).
__device__ inline f32x2v pk_add(f32x2v a, f32x2v b) {
    f32x2v d; asm("v_pk_add_f32 %0, %1, %2" : "=v"(d) : "v"(a), "v"(b)); return d;
}
__device__ inline f32x2v pk_fma(f32x2v a, f32x2v b, f32x2v c) {
    f32x2v d; asm("v_pk_fma_f32 %0, %1, %2, %3" : "=v"(d) : "v"(a), "v"(b), "v"(c)); return d;
}
__device__ inline f32x2v up2v(uint d) {      // 2 packed bf16 -> f32x2v, 2 inst
    f32x2v r; r.x = __uint_as_float(d << 16); r.y = __uint_as_float(d & 0xffff0000u); return r;
}
__device__ inline f32x2v pk_min0(f32x2v a) { // no v_pk_min_f32 -> 2 scalar mins
    f32x2v r; r.x = fminf(a.x, 0.f); r.y = fminf(a.y, 0.f); return r;
}

// ---------------------------------------------------------------------------
// prep (R7 config, best measured): dtype probe + deg zeroing + small-array
// canon + BOTH weight transposes. block roles: [0,NBZ) zero deg |
// [NBZ,NBZ+15) small4 | rest W transpose.
// ---------------------------------------------------------------------------
__global__ __launch_bounds__(256) void prep_kernel(
    const ushort_t* __restrict__ xprobe, int* flag,
    int* __restrict__ deg, int N, int NBZ,
    const void* a0, ushort_t* o0, int n0, const void* a1, ushort_t* o1, int n1,
    const void* a2, ushort_t* o2, int n2, const void* a3, ushort_t* o3, int n3,
    const void* __restrict__ Wl, const void* __restrict__ Wr,
    ushort_t* __restrict__ WtL, ushort_t* __restrict__ WtR, int Kk, int HCk) {
    __shared__ int s_isbf;
    __shared__ ushort_t t[64][72];
    int tid = threadIdx.x;
    if (tid < 64) {
        int hits = 0;
        for (int i = tid; i < 128; i += 64) {
            ushort_t w = xprobe[2 * i];
            uint hb = (w >> 8) & 0x7f;
            hits += (hb >= 0x38 && hb <= 0x42) ? 1 : 0;
        }
        #pragma unroll
        for (int off = 32; off >= 1; off >>= 1) hits += __shfl_xor(hits, off);
        if (tid == 0) s_isbf = (hits >= 64) ? 1 : 0;
    }
    __syncthreads();
    int isbf = s_isbf;
    int b = blockIdx.x;
    if (b == 0 && tid == 0) *flag = isbf;

    if (b < NBZ) {                       // zero deg (int4)
        int i0 = (b * 256 + tid) * 4;
        if (i0 + 4 <= N) *(int4*)&deg[i0] = make_int4(0, 0, 0, 0);
        else for (int j = 0; j < 4; ++j) if (i0 + j < N) deg[i0 + j] = 0;
        return;
    }
    if (b < NBZ + 15) {                  // canon small4
        int idx = (b - NBZ) * 256 + tid;
        const void* srcs[4] = {a0, a1, a2, a3};
        ushort_t* dsts[4] = {o0, o1, o2, o3};
        int ns[4] = {n0, n1, n2, n3};
        #pragma unroll
        for (int k = 0; k < 4; ++k) {
            if (idx < ns[k]) {
                dsts[k][idx] = isbf ? ((const ushort_t*)srcs[k])[idx]
                                    : f2bf(((const float*)srcs[k])[idx]);
                return;
            }
            idx -= ns[k];
        }
        return;
    }
    // W transpose+canon: out[HC][K] = in[K][HC]
    int b2 = b - (NBZ + 15);
    int z = b2 & 1;
    int rest = b2 >> 1;
    int ntk = Kk >> 6;                   // K/64 tiles
    int ky = rest % ntk, nxt = rest / ntk;
    const void* in = z ? Wr : Wl;
    ushort_t* outp = z ? WtR : WtL;
    int kt0 = ky * 64, nt0 = nxt * 64;
    int r = tid >> 3;                    // 0..31
    int c = (tid & 7) * 8;               // 0,8,..,56
    #pragma unroll
    for (int p = 0; p < 2; ++p) {
        int row = r + p * 32;
        size_t base = (size_t)(kt0 + row) * HCk + nt0 + c;
        if (isbf) {
            *(uint4*)&t[row][c] = *(const uint4*)((const ushort_t*)in + base);
        } else {
            const float* f = (const float*)in + base;
            float4 a = *(const float4*)f, bb = *(const float4*)(f + 4);
            ushort_t o[8] = {f2bf(a.x), f2bf(a.y), f2bf(a.z), f2bf(a.w),
                             f2bf(bb.x), f2bf(bb.y), f2bf(bb.z), f2bf(bb.w)};
            *(uint4*)&t[row][c] = *(uint4*)o;
        }
    }
    __syncthreads();
    #pragma unroll
    for (int p = 0; p < 2; ++p) {
        int row = r + p * 32;
        #pragma unroll
        for (int j = 0; j < 8; ++j)
            outp[(size_t)(nt0 + row) * Kk + kt0 + c + j] = t[c + j][row];
    }
}

// ---------------------------------------------------------------------------
// hist + x canon fused: [0,NH) hist atomics | rest: x fp32->bf16 canon.
// ---------------------------------------------------------------------------
__global__ __launch_bounds__(256) void histx_kernel(
    const ushort_t* __restrict__ xprobe,
    const int* __restrict__ dstE, int* deg, int E, int NH, int Ngr,
    const void* __restrict__ xin, ushort_t* __restrict__ xc, long long nx) {
    int tid = threadIdx.x;
    int b = blockIdx.x;
    if (b < NH) {                        // hist
        int i = b * 256 + tid;
        if (i < E) {
            int d = dstE[i];
            if ((uint)d < (uint)Ngr) atomicAdd(&deg[d], 1);
        }
        return;
    }
    __shared__ int s_isbf;
    if (tid < 64) {
        int hits = 0;
        for (int i = tid; i < 128; i += 64) {
            ushort_t w = xprobe[2 * i];
            uint hb = (w >> 8) & 0x7f;
            hits += (hb >= 0x38 && hb <= 0x42) ? 1 : 0;
        }
        #pragma unroll
        for (int off = 32; off >= 1; off >>= 1) hits += __shfl_xor(hits, off);
        if (tid == 0) s_isbf = (hits >= 64) ? 1 : 0;
    }
    __syncthreads();
    if (s_isbf) return;                  // x used directly when already bf16
    long long i0 = ((long long)(b - NH) * 256 + tid) * 8;
    if (i0 + 8 <= nx) {
        const float* f = (const float*)xin + i0;
        float4 a = *(const float4*)f, bb = *(const float4*)(f + 4);
        ushort_t o[8] = {f2bf(a.x), f2bf(a.y), f2bf(a.z), f2bf(a.w),
                         f2bf(bb.x), f2bf(bb.y), f2bf(bb.z), f2bf(bb.w)};
        *(uint4*)&xc[i0] = *(uint4*)o;
    } else {
        for (long long i = i0; i < nx; ++i) xc[i] = f2bf(((const float*)xin)[i]);
    }
}

// phase 1: per-1024-block exclusive scan over (deg[i] + 1)  [+1 = self-loop]
__global__ __launch_bounds__(256) void scan1(const int* __restrict__ deg, int* __restrict__ part,
                                             int* __restrict__ bsum, int N) {
    __shared__ int tmp[256];
    int b = blockIdx.x, tid = threadIdx.x;
    int i0 = b * 1024 + tid * 4;
    int v[4] = {0, 0, 0, 0};
    if (i0 + 4 <= N) { int4 q = *(const int4*)&deg[i0]; v[0]=q.x+1; v[1]=q.y+1; v[2]=q.z+1; v[3]=q.w+1; }
    else { for (int j = 0; j < 4; ++j) v[j] = (i0 + j < N) ? deg[i0 + j] + 1 : 0; }
    int s0 = v[0], s1 = s0 + v[1], s2 = s1 + v[2], s3 = s2 + v[3];
    tmp[tid] = s3;
    __syncthreads();
    for (int off = 1; off < 256; off <<= 1) {
        int t = (tid >= off) ? tmp[tid - off] : 0;
        __syncthreads();
        tmp[tid] += t;
        __syncthreads();
    }
    int base = tid ? tmp[tid - 1] : 0;
    int e[4] = {base, base + s0, base + s1, base + s2};
    if (i0 + 4 <= N) { *(int4*)&part[i0] = make_int4(e[0], e[1], e[2], e[3]); }
    else { for (int j = 0; j < 4; ++j) if (i0 + j < N) part[i0 + j] = e[j]; }
    if (tid == 255) bsum[b] = tmp[255];
}

// phase 2 (fused): each block wave-scans the Nb block sums itself (Nb <= 64)
__global__ __launch_bounds__(256) void scan3(const int* __restrict__ part, const int* __restrict__ bsum,
                                             int* __restrict__ offsets, int* __restrict__ cursor,
                                             int N, int Nb) {
    __shared__ int s_add, s_tot;
    int b = blockIdx.x, tid = threadIdx.x;
    if (tid < 64) {
        int v = (tid < Nb) ? bsum[tid] : 0;
        int incl = v;
        #pragma unroll
        for (int off = 1; off < 64; off <<= 1) {
            int t = __shfl_up(incl, off);
            if (tid >= off) incl += t;
        }
        if (tid == b) s_add = incl - v;
        if (tid == Nb - 1) s_tot = incl;
    }
    __syncthreads();
    int add = s_add;
    int i0 = b * 1024 + tid * 4;
    #pragma unroll
    for (int j = 0; j < 4; ++j) {
        int i = i0 + j;
        if (i < N) { int o = part[i] + add; offsets[i] = o; cursor[i] = o; }
    }
    if (b == Nb - 1 && tid == 0) offsets[N] = s_tot;   // = E + N
}

__global__ void scatter_kernel(const int* __restrict__ src, const int* __restrict__ dst,
                               int* cursor, int* srcs, int E, int N) {
    int i = blockIdx.x * blockDim.x + threadIdx.x;
    if (i >= E + N) return;
    int s, d;
    if (i < E) { s = src[i]; d = dst[i]; }
    else       { s = i - E; d = i - E; }   // self-loop
    if ((uint)d >= (uint)N) return;
    int pos = atomicAdd(&cursor[d], 1);
    if ((uint)pos < (uint)(E + N)) srcs[pos] = s;
}

// ---------------------------------------------------------------------------
// MFMA bf16 GEMM (+ fused scatter rows). C[M,N] = A[M,K] @ Bt[N,K]^T.
// 128x128 tile, 4 waves of 64x64, BK=64. Proven ~115us on this shape.
// ---------------------------------------------------------------------------
__global__ __launch_bounds__(256) void gemm128(const ushort_t* A_bf, const ushort_t* A_cv,
                                               const int* __restrict__ flag,
                                               const ushort_t* __restrict__ Bt,
                                               ushort_t* __restrict__ C,
                                               int M, int Nn, int K, int gyGemm,
                                               const int* __restrict__ esrc,
                                               const int* __restrict__ edst,
                                               int* cursor, int* srcsOut,
                                               int E, int Ngr, int nScB) {
    if ((int)blockIdx.y >= gyGemm) {       // scatter role
        int id = ((int)blockIdx.y - gyGemm) * (int)gridDim.x + (int)blockIdx.x;
        if (id < nScB) {
            int i = id * 256 + (int)threadIdx.x;
            int EN = E + Ngr;
            if (i < EN) {
                int s, d;
                if (i < E) { s = esrc[i]; d = edst[i]; }
                else       { s = i - E; d = i - E; }   // self-loop
                if ((uint)d < (uint)Ngr) {
                    int pos = atomicAdd(&cursor[d], 1);
                    if ((uint)pos < (uint)EN) srcsOut[pos] = s;
                }
            }
        }
        return;
    }
    constexpr int CSTR = 132;                 // epilogue row stride (bank spread)
    __shared__ ushort_t SH[128 * CSTR];       // 33792 B; staging uses first 32KB
    ushort_t* As = SH;                        // As[2][4096]
    ushort_t* Bs = SH + 8192;                 // Bs[2][4096]
    const ushort_t* A = (*flag) ? A_bf : A_cv;
    int tid = threadIdx.x;
    int wave = tid >> 6, lane = tid & 63;
    int row0 = blockIdx.y * 128, col0 = blockIdx.x * 128;
    int wm = (wave >> 1) * 64, wn = (wave & 1) * 64;

    f32x4v acc[4][4];
    #pragma unroll
    for (int i = 0; i < 4; ++i)
        #pragma unroll
        for (int j = 0; j < 4; ++j) acc[i][j] = (f32x4v){0.f, 0.f, 0.f, 0.f};

    int fm = lane & 15, kq8 = (lane >> 4) * 8;

    // staging (coalesced 64B runs): chunk p -> row=p>>2, kp=p&3
    const ushort_t* srcA[2]; ushort_t* dstA0[2]; ushort_t* dstA1[2];
    const ushort_t* srcB[2]; ushort_t* dstB0[2]; ushort_t* dstB1[2];
    #pragma unroll
    for (int i = 0; i < 2; ++i) {
        int p = (wave * 2 + i) * 64 + lane;
        int row = p >> 2, kp = p & 3;
        int gra = row0 + row; if (gra >= M) gra = M - 1;   // tail clamp (C-write guarded)
        srcA[i] = &A[(size_t)gra * K + kp * 8];
        srcB[i] = &Bt[(size_t)(col0 + row) * K + kp * 8];
        dstA0[i] = &As[p * 8]; dstA1[i] = &As[4096 + p * 8];
        dstB0[i] = &Bs[p * 8]; dstB1[i] = &Bs[4096 + p * 8];
    }

    for (int k0 = 0; k0 < K; k0 += 64) {
        #pragma unroll
        for (int i = 0; i < 2; ++i) {
            __builtin_amdgcn_global_load_lds((g_u32_t*)srcA[i],        (lds_u32_t*)dstA0[i], 16, 0, 0);
            __builtin_amdgcn_global_load_lds((g_u32_t*)(srcA[i] + 32), (lds_u32_t*)dstA1[i], 16, 0, 0);
            __builtin_amdgcn_global_load_lds((g_u32_t*)srcB[i],        (lds_u32_t*)dstB0[i], 16, 0, 0);
            __builtin_amdgcn_global_load_lds((g_u32_t*)(srcB[i] + 32), (lds_u32_t*)dstB1[i], 16, 0, 0);
            srcA[i] += 64; srcB[i] += 64;
        }
        __syncthreads();

        #pragma unroll
        for (int panel = 0; panel < 2; ++panel) {
            bf16x8v af[4], bfr[4];
            #pragma unroll
            for (int mi = 0; mi < 4; ++mi)
                af[mi] = *(const bf16x8v*)&As[panel * 4096 + (wm + mi * 16 + fm) * 32 + kq8];
            #pragma unroll
            for (int nj = 0; nj < 4; ++nj)
                bfr[nj] = *(const bf16x8v*)&Bs[panel * 4096 + (wn + nj * 16 + fm) * 32 + kq8];
            #pragma unroll
            for (int mi = 0; mi < 4; ++mi)
                #pragma unroll
                for (int nj = 0; nj < 4; ++nj)
                    acc[mi][nj] = __builtin_amdgcn_mfma_f32_16x16x32_bf16(af[mi], bfr[nj], acc[mi][nj], 0, 0, 0);
        }
        __syncthreads();
    }

    // epilogue: C/D layout col = lane&15, row = (lane>>4)*4 + r
    int col = lane & 15, rq = (lane >> 4) * 4;
    #pragma unroll
    for (int mi = 0; mi < 4; ++mi)
        #pragma unroll
        for (int r = 0; r < 4; ++r)
            #pragma unroll
            for (int nj = 0; nj < 4; ++nj)
                SH[(wm + mi * 16 + rq + r) * CSTR + wn + nj * 16 + col] = f2bf(acc[mi][nj][r]);
    __syncthreads();
    #pragma unroll
    for (int j = 0; j < 8; ++j) {
        int base = (tid + j * 256) * 8;        // idx in 128x128 space
        int r = base >> 7, c = base & 127;
        int gm = row0 + r;
        if (gm < M)
            *(uint4*)&C[(size_t)gm * Nn + col0 + c] = *(const uint4*)&SH[r * CSTR + c];
    }
}

// ---------------------------------------------------------------------------
// gat (R7 config, best measured 116.8us — R11's depth-4 prefetch REFUTED,
// +4us: extra clamped-index/address VALU on a kernel where VALU and gather
// latency are balanced). 2 waves/node, 2 heads/wave, 16 ch/lane, packed-f32
// channel math, intra-half butterfly, 2-edge-pair prefetch, nt xr loads.
// ---------------------------------------------------------------------------
__global__ __launch_bounds__(128, 4) void gat_aggregate(
    const ushort_t* __restrict__ xl, int xl_stride,
    const ushort_t* __restrict__ xr, int xr_stride,
    const int* __restrict__ offsets, const int* __restrict__ srcs,
    const ushort_t* __restrict__ att, const ushort_t* __restrict__ bias,
    const ushort_t* __restrict__ Wc, const ushort_t* __restrict__ bc,
    float* __restrict__ out, int c0, int Cn, int N, int EN) {
    int bn = blockIdx.x;
    if (bn >= Cn) return;
    int n = c0 + bn;
    int tid = threadIdx.x;
    int w = tid >> 6, lane = tid & 63;
    int h = 2 * w + (lane >> 5);             // this lane's head
    int r = lane & 31;                       // 32 lanes per head
    int hoff = h * FEAT + r * 16;            // 16 channels per lane

    __shared__ float sh[HEADS][FEAT];
    __shared__ float r0s[2], r1s[2];

    f32x2v xrr[8], attr[8];
    { const uint4v* p = (const uint4v*)&xr[(size_t)bn * xr_stride + hoff];
      uint4v qa = __builtin_nontemporal_load(p);          // xr read exactly once
      uint4v qb = __builtin_nontemporal_load(p + 1);
      xrr[0] = up2v(qa.x); xrr[1] = up2v(qa.y); xrr[2] = up2v(qa.z); xrr[3] = up2v(qa.w);
      xrr[4] = up2v(qb.x); xrr[5] = up2v(qb.y); xrr[6] = up2v(qb.z); xrr[7] = up2v(qb.w); }
    { const ushort_t* p = &att[hoff];
      uint4 qa = *(const uint4*)p, qb = *(const uint4*)(p + 8);
      attr[0] = up2v(qa.x); attr[1] = up2v(qa.y); attr[2] = up2v(qa.z); attr[3] = up2v(qa.w);
      attr[4] = up2v(qb.x); attr[5] = up2v(qb.y); attr[6] = up2v(qb.z); attr[7] = up2v(qb.w); }

    int start = offsets[n], end = offsets[n + 1];
    start = max(0, min(start, EN));
    end   = max(start, min(end, EN));
    int deg = end - start;

    int sv = 0;
    if (lane < deg) sv = srcs[start + lane];

    float l = 0.f;
    f32x2v acc[8] = {{0.f,0.f},{0.f,0.f},{0.f,0.f},{0.f,0.f},
                     {0.f,0.f},{0.f,0.f},{0.f,0.f},{0.f,0.f}};
    const ushort_t* xlh = xl + hoff;
    const f32x2v cneg = {NEG - 1.0f, NEG - 1.0f};

    auto getS = [&](int i) -> int {
        if (i >= deg) i = deg - 1;
        if (i < 0) i = 0;
        int s = (i < 64) ? __shfl(sv, i) : srcs[start + i];
        return ((uint)s >= (uint)N) ? 0 : s;
    };
    auto fetchE = [&](int i, uint4& qa, uint4& qb) {
        int s = getS(i);
        const ushort_t* pp = xlh + (size_t)s * xl_stride;
        qa = *(const uint4*)pp;
        qb = *(const uint4*)(pp + 8);
    };
    auto body = [&](uint4 qa, uint4 qb) {
        f32x2v v[8] = {up2v(qa.x), up2v(qa.y), up2v(qa.z), up2v(qa.w),
                       up2v(qb.x), up2v(qb.y), up2v(qb.z), up2v(qb.w)};
        f32x2v p2 = {0.f, 0.f};
        #pragma unroll
        for (int j = 0; j < 8; ++j) {
            f32x2v u  = pk_add(v[j], xrr[j]);
            f32x2v lr = pk_fma(pk_min0(u), cneg, u);   // packed LeakyReLU
            p2 = pk_fma(lr, attr[j], p2);
        }
        float p = p2.x + p2.y;
        #pragma unroll
        for (int off = 16; off >= 1; off >>= 1) p += __shfl_xor(p, off);  // intra-half
        float wgt = __expf(p);
        l += wgt;
        f32x2v wv2; wv2.x = wgt; wv2.y = wgt;
        #pragma unroll
        for (int j = 0; j < 8; ++j) acc[j] = pk_fma(wv2, v[j], acc[j]);
    };

    uint4 a0q, a0r, a1q, a1r, b0q, b0r, b1q, b1r;
    fetchE(0, a0q, a0r);
    fetchE(1, a1q, a1r);
    for (int e = 0; e < deg; e += 2) {
        fetchE(e + 2, b0q, b0r);     // clamped on tail -> L1 hit, discarded
        fetchE(e + 3, b1q, b1r);
        body(a0q, a0r);
        if (e + 1 < deg) body(a1q, a1r);
        a0q = b0q; a0r = b0r; a1q = b1q; a1r = b1r;
    }

    float inv = 0.25f / fmaxf(l, 1e-35f);   // 1/l, mean over heads folded in
    #pragma unroll
    for (int j = 0; j < 8; ++j) {
        sh[h][r * 16 + 2 * j]     = acc[j].x * inv;
        sh[h][r * 16 + 2 * j + 1] = acc[j].y * inv;
    }
    __syncthreads();

    float p0 = 0.f, p1 = 0.f;
    #pragma unroll
    for (int c = tid; c < FEAT; c += 128) {
        float f = sh[0][c] + sh[1][c] + sh[2][c] + sh[3][c] + bf2f(bias[c]);
        uint w2 = *(const uint*)&Wc[c * 2];
        p0 = fmaf(f, bf2f((ushort_t)(w2 & 0xffff)), p0);
        p1 = fmaf(f, bf2f((ushort_t)(w2 >> 16)), p1);
    }
    #pragma unroll
    for (int off = 32; off >= 1; off >>= 1) {
        p0 += __shfl_xor(p0, off);
        p1 += __shfl_xor(p1, off);
    }
    if (lane == 0) { r0s[w] = p0; r1s[w] = p1; }
    __syncthreads();
    if (tid == 0) {
        out[(size_t)n * 2 + 0] = r0s[0] + r0s[1] + bf2f(bc[0]);
        out[(size_t)n * 2 + 1] = r1s[0] + r1s[1] + bf2f(bc[1]);
    }
}

// ---------------------------------------------------------------------------
extern "C" void kernel_launch(void* const* d_in, const int* in_sizes, int n_in,
                              void* d_out, int out_size, void* d_ws, size_t ws_size,
                              hipStream_t stream) {
    const void* x    = d_in[0];
    const int*  ei   = (const int*)d_in[1];
    const void* W_l  = d_in[2];
    const void* W_r  = d_in[3];
    const void* att  = d_in[4];
    const void* bias = d_in[5];
    const void* Wc   = d_in[6];
    const void* bc   = d_in[7];
    float* out = (float*)d_out;

    const int N  = in_sizes[0] / FEAT;     // 20000
    const int E  = in_sizes[1] / 2;        // 160000
    const int K  = FEAT;                   // 512
    const int HC = HEADS * FEAT;           // 2048
    const int EN = E + N;
    const int Nb = (N + 1023) / 1024;      // scan blocks (20 <= 64)

    const int* src = ei;
    const int* dst = ei + E;

    // ---- adaptive workspace layout ----
    char* base = (char*)d_ws;
    size_t off = 0;
    auto alloc = [&](size_t bytes) -> char* {
        char* p = base + off;
        off = (off + bytes + 255) & ~(size_t)255;
        return p;
    };
    int* flag    = (int*)alloc(4);
    int* offsets = (int*)alloc((size_t)(N + 1) * 4);
    int* cursor  = (int*)alloc((size_t)N * 4);
    int* deg     = (int*)alloc((size_t)N * 4);
    int* part    = (int*)alloc((size_t)N * 4);
    int* bsum    = (int*)alloc((size_t)(Nb + 1) * 4);
    int* srcs    = (int*)alloc((size_t)EN * 4);
    ushort_t* attc  = (ushort_t*)alloc((size_t)HC * 2);
    ushort_t* biasc = (ushort_t*)alloc((size_t)FEAT * 2);
    ushort_t* Wcc   = (ushort_t*)alloc((size_t)FEAT * 2 * 2);
    ushort_t* bcc   = (ushort_t*)alloc(2 * 2);
    ushort_t* xc   = (ushort_t*)alloc((size_t)N * K * 2);
    ushort_t* Wcat = (ushort_t*)alloc((size_t)2 * HC * K * 2);   // [Wl^T ; Wr^T]
    size_t fixed = off;

    size_t need_merged = (size_t)N * 2 * HC * 2;
    bool merged = (ws_size >= fixed + need_merged);

    // 0) prep: probe + deg-zero + small canon + W transpose
    long long NX = (long long)N * K;
    const int NBZ = (N + 1023) / 1024;                       // deg-zero blocks
    const int nT = (HC / 64) * (K / 64) * 2;                 // 512 transpose blocks
    prep_kernel<<<NBZ + 15 + nT, 256, 0, stream>>>(
        (const ushort_t*)x, flag, deg, N, NBZ,
        att, attc, HC, bias, biasc, FEAT, Wc, Wcc, FEAT * 2, bc, bcc, 2,
        W_l, W_r, Wcat, Wcat + (size_t)HC * K, K, HC);

    // 1) hist + x canon fused (both depend only on prep)
    const int NH = (E + 255) / 256;
    int nxb = (int)((NX / 8 + 255) / 256);
    histx_kernel<<<NH + nxb, 256, 0, stream>>>(
        (const ushort_t*)x, dst, deg, E, NH, N, x, xc, NX);

    // 2) scans
    scan1<<<Nb, 256, 0, stream>>>(deg, part, bsum, N);
    scan3<<<Nb, 256, 0, stream>>>(part, bsum, offsets, cursor, N, Nb);

    const ushort_t* x_bf = (const ushort_t*)x;
    const int nScB = (EN + 255) / 256;                       // scatter blocks

    if (merged) {
        ushort_t* xlr = (ushort_t*)(base + fixed);       // N x 4096: [xl | xr]
        int gx = 2 * HC / 128;                           // 32
        int gyG = (N + 127) / 128;                       // 157
        int exR = (nScB + gx - 1) / gx;                  // 22 scatter rows
        dim3 gg(gx, gyG + exR);
        // 3) gemm + fused scatter (scatter needs only scan3; overlaps gemm)
        gemm128<<<gg, 256, 0, stream>>>(x_bf, xc, flag, Wcat, xlr, N, 2 * HC, K,
                                        gyG, src, dst, cursor, srcs, E, N, nScB);
        // 4) gat
        gat_aggregate<<<N, 128, 0, stream>>>(xlr, 2 * HC, xlr + HC, 2 * HC,
                                             offsets, srcs, attc, biasc, Wcc, bcc,
                                             out, 0, N, N, EN);
    } else {
        // fallback: separate scatter + xl + chunked xr
        scatter_kernel<<<nScB, 256, 0, stream>>>(src, dst, cursor, srcs, E, N);
        ushort_t* xl = (ushort_t*)alloc((size_t)N * HC * 2);
        size_t remain = (ws_size > off) ? (ws_size - off) : 0;
        long long Cmax = (long long)(remain / ((size_t)HC * 2));
        int C = (Cmax >= N) ? N : (int)(Cmax & ~63LL);
        if (C < 64) C = 64;
        ushort_t* xrc = (ushort_t*)(base + off);
        ushort_t* Wlt = Wcat;
        ushort_t* Wrt = Wcat + (size_t)HC * K;

        dim3 gl(HC / 128, (N + 127) / 128);
        gemm128<<<gl, 256, 0, stream>>>(x_bf, xc, flag, Wlt, xl, N, HC, K,
                                        (N + 127) / 128, nullptr, nullptr,
                                        nullptr, nullptr, 0, 0, 0);
        for (int c0 = 0; c0 < N; c0 += C) {
            int Cn = (N - c0 < C) ? (N - c0) : C;
            dim3 gr(HC / 128, (Cn + 127) / 128);
            gemm128<<<gr, 256, 0, stream>>>(x_bf + (size_t)c0 * K, xc + (size_t)c0 * K, flag,
                                            Wrt, xrc, Cn, HC, K,
                                            (Cn + 127) / 128, nullptr, nullptr,
                                            nullptr, nullptr, 0, 0, 0);
            gat_aggregate<<<Cn, 128, 0, stream>>>(xl, HC, xrc, HC,
                                                  offsets, srcs, attc, biasc, Wcc, bcc,
                                                  out, c0, Cn, N, EN);
        }
    }
}